// Round 1
// 748.761 us; speedup vs baseline: 2.2532x; 2.2532x over previous
//
#include <hip/hip_runtime.h>
#include <hip/hip_bf16.h>
#include <hip/hip_fp16.h>

// ---------------------------------------------------------------------------
// FCLSTM: x(256,300,64,3) -> transpose -> LSTM(900->256,relu) -> LSTM(256->256)
//         -> Dense(256->600) -> out (256,300,64,2)
// Phases:
//   P0 sniff dtype (f32 vs bf16 buffers) + zero sync flags
//   P1 prep: bias cvt, weight transpose/cast to f16 "K-major" (N x K)
//   P2 transpose x -> xt (16384 x 928 f16, zero-padded K)
//   P3 GEMM zx0 = xt @ W0 + b0            (16384x1024, K=928)
//   P4 LSTM0 recurrence (paired-block, U in VGPRs, fence-free MALL handshake)
//   P5 GEMM zx1 = h0 @ W1 + b1            (16384x1024, K=256)
//   P6 LSTM1 recurrence -> h1 seq
//   P7 GEMM out = h1 @ Wd + bd, scatter to (B,N,T,F) layout, f32 or bf16
// ---------------------------------------------------------------------------

typedef _Float16 half8 __attribute__((ext_vector_type(8)));
typedef float floatx4 __attribute__((ext_vector_type(4)));

#define B_SZ   256
#define T_STEPS 64
#define N_SEQ  300
#define M_ROWS 16384   // B*T
#define K0P    928     // padded 300*3=900
#define G4     1024    // 4*256 gate width
#define UD     256
#define NOUT   600
#define NOUTP  640

// ---- workspace layout (bytes) ----
#define OFF_MODE   ((size_t)0)
#define OFF_FLAGS  ((size_t)256)                   // 64 u32 (2 layers x 32)
#define OFF_BIAS   ((size_t)512)                   // 2648 f32
#define OFF_XT     ((size_t)16384)
#define SZ_XT      ((size_t)M_ROWS * K0P * 2)      // 30,408,704
#define OFF_W0T    (OFF_XT + SZ_XT)
#define SZ_W0T     ((size_t)G4 * K0P * 2)          // 1,900,544
#define OFF_U0T    (OFF_W0T + SZ_W0T)
#define SZ_UT      ((size_t)G4 * UD * 2)           // 524,288
#define OFF_W1T    (OFF_U0T + SZ_UT)
#define OFF_U1T    (OFF_W1T + SZ_UT)
#define OFF_WDT    (OFF_U1T + SZ_UT)
#define SZ_WDT     ((size_t)NOUTP * UD * 2)        // 327,680
#define OFF_HBUF   (OFF_WDT + SZ_WDT)
#define SZ_HBUF    ((size_t)16 * 2 * 2 * 4096)     // 262,144 (payload: g x c x parity x 4KB)
#define OFF_ZX0    (OFF_HBUF + SZ_HBUF)
#define SZ_ZX      ((size_t)M_ROWS * G4 * 2)       // 33,554,432
#define OFF_H0     (OFF_ZX0 + SZ_ZX)
#define SZ_H       ((size_t)M_ROWS * UD * 2)       // 8,388,608
#define OFF_ZX1    (OFF_H0 + SZ_H)
#define OFF_H1     (OFF_ZX1 + SZ_ZX)
#define WS_NEEDED  (OFF_H1 + SZ_H)

__device__ __forceinline__ float load_in(const void* p, size_t idx, int mode) {
  if (mode) {
    unsigned v = ((const unsigned short*)p)[idx];
    return __uint_as_float(v << 16);
  }
  return ((const float*)p)[idx];
}

// ---- P0: dtype sniff + flag zeroing --------------------------------------
__global__ void sniff_init(const unsigned* __restrict__ x, int* __restrict__ modeflag,
                           unsigned* __restrict__ flags) {
  __shared__ int cnt;
  if (threadIdx.x == 0) cnt = 0;
  __syncthreads();
  unsigned w = x[threadIdx.x];          // 256 words of x
  unsigned e = (w >> 8) & 0x7fu;        // bits 8..14: bf16 sign-dropped exp[7:1] if bf16
  if (e >= 0x3au && e <= 0x42u) atomicAdd(&cnt, 1);
  __syncthreads();
  if (threadIdx.x == 0) *modeflag = (cnt >= 128) ? 1 : 0;   // 1 = bf16 buffers
  if (threadIdx.x < 64) flags[threadIdx.x] = 0u;
}

// ---- P1a: bias convert ----------------------------------------------------
__global__ void cvt_bias(const void* __restrict__ b0, const void* __restrict__ b1,
                         const void* __restrict__ bd, float* __restrict__ outb,
                         const int* __restrict__ modeflag) {
  int mode = *modeflag;
  int i = blockIdx.x * 256 + threadIdx.x;
  if (i < 1024)       outb[i] = load_in(b0, i, mode);
  else if (i < 2048)  outb[i] = load_in(b1, i - 1024, mode);
  else if (i < 2648)  outb[i] = load_in(bd, i - 2048, mode);
}

// ---- P1b: generic transpose+cast: out[n*Kout+k] = in[k*Cin+n] (0 padded) --
__global__ void transpose_cast(const void* __restrict__ in, _Float16* __restrict__ out,
                               int Rin, int Cin, int Nout, int Kout,
                               const int* __restrict__ modeflag) {
  int mode = *modeflag;
  __shared__ float tile[32][33];
  int k0 = blockIdx.x * 32, n0 = blockIdx.y * 32;
  int tx = threadIdx.x, ty = threadIdx.y;
  #pragma unroll
  for (int i = 0; i < 32; i += 8) {
    int k = k0 + ty + i, n = n0 + tx;
    tile[ty + i][tx] = (k < Rin && n < Cin) ? load_in(in, (size_t)k * Cin + n, mode) : 0.f;
  }
  __syncthreads();
  #pragma unroll
  for (int i = 0; i < 32; i += 8) {
    int n = n0 + ty + i, k = k0 + tx;
    if (n < Nout && k < Kout)
      out[(size_t)n * Kout + k] = (_Float16)tile[tx][ty + i];
  }
}

// ---- P2: x (B,N,T,F) f32/bf16 -> xt (B*T, 928) f16 ------------------------
__global__ void transpose_x(const void* __restrict__ x, _Float16* __restrict__ xt,
                            const int* __restrict__ modeflag) {
  int mode = *modeflag;
  int b = blockIdx.y, ch = blockIdx.x;    // 5 chunks of 60 n each
  __shared__ _Float16 tile[60 * 192];     // [nn][t][f]
  int n0 = ch * 60;
  size_t basein = ((size_t)b * N_SEQ + n0) * 192;
  for (int i = threadIdx.x; i < 60 * 192; i += 256)
    tile[i] = (_Float16)load_in(x, basein + i, mode);
  __syncthreads();
  for (int i = threadIdx.x; i < 64 * 180; i += 256) {
    int t = i / 180, cz = i % 180;        // cz = nn*3+f
    int nn = cz / 3, f = cz % 3;
    xt[((size_t)b * 64 + t) * K0P + n0 * 3 + cz] = tile[nn * 192 + t * 3 + f];
  }
  if (ch == 4) {  // zero pad cols 900..927
    for (int i = threadIdx.x; i < 64 * 28; i += 256) {
      int t = i / 28, z = i % 28;
      xt[((size_t)b * 64 + t) * K0P + 900 + z] = (_Float16)0.f;
    }
  }
}

// ---- P3/P5/P7: f16 MFMA GEMM, 128x128 tile, 4 waves, BK=32 ----------------
// A: MxK f16 row-major. BT: NxK f16 row-major (i.e. B transposed, K-major).
// OUT_MODE 0: store f16 C[row*N+col] (+bias).  OUT_MODE 1: scatter to d_out.
template <int OUT_MODE>
__global__ __launch_bounds__(256)
void gemm_f16(const _Float16* __restrict__ A, const _Float16* __restrict__ BT,
              const float* __restrict__ bias, void* __restrict__ Cout,
              int N, int K, int Nreal, const int* __restrict__ modeflag) {
  __shared__ _Float16 As[128 * 40];
  __shared__ _Float16 Bs[128 * 40];
  int tid = threadIdx.x;
  int wv = tid >> 6, lane = tid & 63;
  int q = lane >> 4, l15 = lane & 15;
  int wm = wv >> 1, wn = wv & 1;
  int row0 = blockIdx.y * 128, col0 = blockIdx.x * 128;
  floatx4 acc[4][4] = {};
  int r_st = tid >> 1;            // staged row/col 0..127
  int c_st = (tid & 1) * 2;       // 16B chunk 0 or 2
  const _Float16* Arow = A + (size_t)(row0 + r_st) * K + c_st * 8;
  const _Float16* Brow = BT + (size_t)(col0 + r_st) * K + c_st * 8;
  _Float16* AsW = As + r_st * 40 + c_st * 8;
  _Float16* BsW = Bs + r_st * 40 + c_st * 8;

  for (int k0 = 0; k0 < K; k0 += 32) {
    __syncthreads();
    half8 a0 = *(const half8*)(Arow + k0);
    half8 a1 = *(const half8*)(Arow + k0 + 8);
    half8 b0v = *(const half8*)(Brow + k0);
    half8 b1v = *(const half8*)(Brow + k0 + 8);
    *(half8*)(AsW) = a0;  *(half8*)(AsW + 8) = a1;
    *(half8*)(BsW) = b0v; *(half8*)(BsW + 8) = b1v;
    __syncthreads();
    half8 af[4], bf[4];
    #pragma unroll
    for (int i = 0; i < 4; ++i)
      af[i] = *(const half8*)(As + (wm * 64 + i * 16 + l15) * 40 + q * 8);
    #pragma unroll
    for (int j = 0; j < 4; ++j)
      bf[j] = *(const half8*)(Bs + (wn * 64 + j * 16 + l15) * 40 + q * 8);
    #pragma unroll
    for (int i = 0; i < 4; ++i)
      #pragma unroll
      for (int j = 0; j < 4; ++j)
        acc[i][j] = __builtin_amdgcn_mfma_f32_16x16x32_f16(af[i], bf[j], acc[i][j], 0, 0, 0);
  }

  int mode = 0;
  if (OUT_MODE == 1) mode = *modeflag;
  #pragma unroll
  for (int j = 0; j < 4; ++j) {
    int col = col0 + wn * 64 + j * 16 + l15;
    float bv = (col < Nreal) ? bias[col] : 0.f;
    #pragma unroll
    for (int i = 0; i < 4; ++i) {
      int rowb = row0 + wm * 64 + i * 16 + q * 4;
      #pragma unroll
      for (int r = 0; r < 4; ++r) {
        float v = acc[i][j][r] + bv;
        int row = rowb + r;
        if (OUT_MODE == 0) {
          ((_Float16*)Cout)[(size_t)row * N + col] = (_Float16)v;
        } else {
          if (col < Nreal) {
            // row = b*64+t ; col = n*2+f ; out[((b*300+n)*64+t)*2+f]
            size_t idx = (size_t)(row >> 6) * 38400 + (size_t)(col >> 1) * 128
                       + (size_t)(row & 63) * 2 + (col & 1);
            if (mode) ((__hip_bfloat16*)Cout)[idx] = __float2bfloat16(v);
            else      ((float*)Cout)[idx] = v;
          }
        }
      }
    }
  }
}

// ---- P4/P6: LSTM recurrence (fence-free handshake) ------------------------
// 16 groups (16 batch rows each) x 2 blocks (128 units each). 512 thr = 8 waves.
// Wave w holds U columns for its 16 units x 4 gates as MFMA B-frags in VGPRs.
// Cross-block h exchange: RELAXED agent-scope u64 atomics (write-through to the
// coherence point) -> no threadfence, no per-step buffer_wbl2/inv.
// Own-half h exchange: XOR-swizzled LDS, double-buffered, one barrier/step.
__global__ __launch_bounds__(512, 2)
void lstm_rec(const _Float16* __restrict__ zx, const _Float16* __restrict__ UT,
              _Float16* __restrict__ hseq, unsigned long long* __restrict__ pay,
              unsigned* __restrict__ flags) {
  int tid = threadIdx.x;
  int wv = tid >> 6, lane = tid & 63;
  int q = lane >> 4, l15 = lane & 15;
  int c = blockIdx.x >> 4;       // pair half 0/1
  int g = blockIdx.x & 15;       // batch group
  int ubase = c * 128 + wv * 16; // wave's unit base within 256
  int ucol = ubase + l15;

  __shared__ _Float16 hlds[2][16 * 128];   // own-half h, XOR-swizzled, 2 x 4KB

  half8 uf[4][8];
  #pragma unroll
  for (int G = 0; G < 4; ++G) {
    const _Float16* Urow = UT + (size_t)(G * 256 + ucol) * UD;
    #pragma unroll
    for (int s = 0; s < 8; ++s)
      uf[G][s] = *(const half8*)(Urow + s * 32 + q * 8);
  }
  half8 hf[8];
  #pragma unroll
  for (int s = 0; s < 8; ++s) hf[s] = (half8)(_Float16)0.f;
  floatx4 cst = {0.f, 0.f, 0.f, 0.f};

  unsigned* myflag = &flags[g * 2 + c];
  unsigned* pflag  = &flags[g * 2 + (1 - c)];
  unsigned long long* mypay = pay + (size_t)(g * 2 + c) * 1024;        // 2x512 u64
  const unsigned long long* ppay = pay + (size_t)(g * 2 + (1 - c)) * 1024;

  // transpose-target coords: this lane will own (row, colquad) after the
  // in-quad 4x4 f16 transpose. row = batch row 0..15, colquad = 4 cols.
  int row = q * 4 + (lane & 3);
  int cq  = l15 & 12;
  int payi  = row * 32 + ((wv * 16 + cq) >> 2);                        // u64 idx
  int ldswb = (row * 256 + (wv * 16 + cq) * 2) ^ ((row & 7) << 4);     // swz byte
  unsigned long long* hsp =
      (unsigned long long*)(hseq + ((size_t)(g * 16 + row) * 64) * UD + ubase + cq);
  const _Float16* zb = zx + (size_t)(g * 16 + q * 4) * 64 * G4 + ucol;

  // zx prefetch registers (one timestep ahead)
  unsigned short zpre[16];
  #pragma unroll
  for (int G = 0; G < 4; ++G)
    #pragma unroll
    for (int r = 0; r < 4; ++r)
      zpre[G * 4 + r] = *(const unsigned short*)(zb + r * (64 * G4) + G * 256);

  for (int t = 0; t < 64; ++t) {
    floatx4 accv[4] = {};
    // own-half slices first so LDS-sourced MFMAs overlap in-flight MALL loads
    if (c == 0) {
      #pragma unroll
      for (int s = 0; s < 8; ++s) {
        accv[0] = __builtin_amdgcn_mfma_f32_16x16x32_f16(hf[s], uf[0][s], accv[0], 0, 0, 0);
        accv[1] = __builtin_amdgcn_mfma_f32_16x16x32_f16(hf[s], uf[1][s], accv[1], 0, 0, 0);
        accv[2] = __builtin_amdgcn_mfma_f32_16x16x32_f16(hf[s], uf[2][s], accv[2], 0, 0, 0);
        accv[3] = __builtin_amdgcn_mfma_f32_16x16x32_f16(hf[s], uf[3][s], accv[3], 0, 0, 0);
      }
    } else {
      #pragma unroll
      for (int ss = 0; ss < 8; ++ss) {
        int s = (ss + 4) & 7;   // 4,5,6,7,0,1,2,3 — constant after unroll
        accv[0] = __builtin_amdgcn_mfma_f32_16x16x32_f16(hf[s], uf[0][s], accv[0], 0, 0, 0);
        accv[1] = __builtin_amdgcn_mfma_f32_16x16x32_f16(hf[s], uf[1][s], accv[1], 0, 0, 0);
        accv[2] = __builtin_amdgcn_mfma_f32_16x16x32_f16(hf[s], uf[2][s], accv[2], 0, 0, 0);
        accv[3] = __builtin_amdgcn_mfma_f32_16x16x32_f16(hf[s], uf[3][s], accv[3], 0, 0, 0);
      }
    }

    _Float16 hh[4];
    #pragma unroll
    for (int r = 0; r < 4; ++r) {
      float zi = accv[0][r] + (float)__builtin_bit_cast(_Float16, zpre[0 + r]);
      float zf = accv[1][r] + (float)__builtin_bit_cast(_Float16, zpre[4 + r]);
      float zg = accv[2][r] + (float)__builtin_bit_cast(_Float16, zpre[8 + r]);
      float zo = accv[3][r] + (float)__builtin_bit_cast(_Float16, zpre[12 + r]);
      float ig = 1.f / (1.f + __expf(-zi));
      float fg = 1.f / (1.f + __expf(-zf));
      float gg = zg > 0.f ? zg : 0.f;
      float og = 1.f / (1.f + __expf(-zo));
      float cn = fg * cst[r] + ig * gg;
      cst[r] = cn;
      hh[r] = (_Float16)(og * (cn > 0.f ? cn : 0.f));
    }

    // 4x4 in-quad f16 transpose: lane(q,l15) holds col ucol rows q*4..+3;
    // after 2 shfl_xor each lane holds row q*4+(lane&3), cols ubase+cq..+3 (u64)
    unsigned A  = ((unsigned)__builtin_bit_cast(unsigned short, hh[1]) << 16)
                |  (unsigned)__builtin_bit_cast(unsigned short, hh[0]);
    unsigned Bq = ((unsigned)__builtin_bit_cast(unsigned short, hh[3]) << 16)
                |  (unsigned)__builtin_bit_cast(unsigned short, hh[2]);
    unsigned T  = __shfl_xor((lane & 2) ? A : Bq, 2, 64);
    unsigned X0 = (lane & 2) ? T : A;    // left col pair (rows r,r+1)
    unsigned X1 = (lane & 2) ? Bq : T;   // right col pair
    unsigned W  = (X0 & 0xffffu) | (X1 << 16);          // even row of pair
    unsigned X  = (X0 >> 16) | (X1 & 0xffff0000u);      // odd  row of pair
    unsigned R  = __shfl_xor((lane & 1) ? W : X, 1, 64);
    unsigned lo, hi;
    if (lane & 1) { lo = (R & 0xffffu) | (X << 16); hi = (R >> 16) | (X & 0xffff0000u); }
    else          { lo = (W & 0xffffu) | (R << 16); hi = (W >> 16) | (R & 0xffff0000u); }
    unsigned long long hp = ((unsigned long long)hi << 32) | lo;

    hsp[(size_t)t * 64] = hp;                    // hseq: fire-and-forget

    if (t < 63) {
      int par = t & 1;
      // payload to partner: relaxed agent atomic (write-through, no fence)
      __hip_atomic_store(mypay + par * 512 + payi, hp, __ATOMIC_RELAXED,
                         __HIP_MEMORY_SCOPE_AGENT);
      // own half into swizzled LDS
      *(unsigned long long*)((char*)hlds + par * 4096 + ldswb) = hp;
      // prefetch zx for t+1 (hidden under drain/poll/next MFMA)
      #pragma unroll
      for (int G = 0; G < 4; ++G)
        #pragma unroll
        for (int r = 0; r < 4; ++r)
          zpre[G * 4 + r] =
              *(const unsigned short*)(zb + r * (64 * G4) + (t + 1) * G4 + G * 256);
      // barrier drains vmcnt(0): payload at coherence point, LDS visible
      __syncthreads();
      if (tid == 0)
        __hip_atomic_store(myflag, (unsigned)(t + 1), __ATOMIC_RELAXED,
                           __HIP_MEMORY_SCOPE_AGENT);
      while (__hip_atomic_load(pflag, __ATOMIC_RELAXED, __HIP_MEMORY_SCOPE_AGENT)
             <= (unsigned)t)
        __builtin_amdgcn_s_sleep(1);
      asm volatile("" ::: "memory");   // no hoist of payload loads above poll
      const unsigned long long* pp = ppay + par * 512;
      if (c == 0) {
        #pragma unroll
        for (int sl = 0; sl < 4; ++sl) {     // partner half -> slices 4..7
          union { unsigned long long u[2]; half8 v; } cv;
          cv.u[0] = __hip_atomic_load(pp + (l15 * 32 + sl * 8 + q * 2),
                                      __ATOMIC_RELAXED, __HIP_MEMORY_SCOPE_AGENT);
          cv.u[1] = __hip_atomic_load(pp + (l15 * 32 + sl * 8 + q * 2 + 1),
                                      __ATOMIC_RELAXED, __HIP_MEMORY_SCOPE_AGENT);
          hf[4 + sl] = cv.v;
        }
        #pragma unroll
        for (int sl = 0; sl < 4; ++sl) {     // own half (LDS) -> slices 0..3
          int rb = (l15 * 256 + sl * 64 + q * 16) ^ ((l15 & 7) << 4);
          hf[sl] = *(const half8*)((const char*)hlds + par * 4096 + rb);
        }
      } else {
        #pragma unroll
        for (int sl = 0; sl < 4; ++sl) {     // partner half -> slices 0..3
          union { unsigned long long u[2]; half8 v; } cv;
          cv.u[0] = __hip_atomic_load(pp + (l15 * 32 + sl * 8 + q * 2),
                                      __ATOMIC_RELAXED, __HIP_MEMORY_SCOPE_AGENT);
          cv.u[1] = __hip_atomic_load(pp + (l15 * 32 + sl * 8 + q * 2 + 1),
                                      __ATOMIC_RELAXED, __HIP_MEMORY_SCOPE_AGENT);
          hf[sl] = cv.v;
        }
        #pragma unroll
        for (int sl = 0; sl < 4; ++sl) {     // own half (LDS) -> slices 4..7
          int rb = (l15 * 256 + sl * 64 + q * 16) ^ ((l15 & 7) << 4);
          hf[4 + sl] = *(const half8*)((const char*)hlds + par * 4096 + rb);
        }
      }
    }
  }
}

// ---------------------------------------------------------------------------
extern "C" void kernel_launch(void* const* d_in, const int* in_sizes, int n_in,
                              void* d_out, int out_size, void* d_ws, size_t ws_size,
                              hipStream_t stream) {
  if (ws_size < WS_NEEDED) return;  // fail loudly via wrong output rather than OOB

  const void* x  = d_in[0];
  const void* W0 = d_in[1];
  const void* U0 = d_in[2];
  const void* b0 = d_in[3];
  const void* W1 = d_in[4];
  const void* U1 = d_in[5];
  const void* b1 = d_in[6];
  const void* Wd = d_in[7];
  const void* bd = d_in[8];

  char* ws = (char*)d_ws;
  int*       mf    = (int*)(ws + OFF_MODE);
  unsigned*  flags = (unsigned*)(ws + OFF_FLAGS);
  float*     biasf = (float*)(ws + OFF_BIAS);
  _Float16*  xt    = (_Float16*)(ws + OFF_XT);
  _Float16*  W0T   = (_Float16*)(ws + OFF_W0T);
  _Float16*  U0T   = (_Float16*)(ws + OFF_U0T);
  _Float16*  W1T   = (_Float16*)(ws + OFF_W1T);
  _Float16*  U1T   = (_Float16*)(ws + OFF_U1T);
  _Float16*  WdT   = (_Float16*)(ws + OFF_WDT);
  unsigned long long* pay = (unsigned long long*)(ws + OFF_HBUF);
  _Float16*  zx0   = (_Float16*)(ws + OFF_ZX0);
  _Float16*  h0    = (_Float16*)(ws + OFF_H0);
  _Float16*  zx1   = (_Float16*)(ws + OFF_ZX1);
  _Float16*  h1    = (_Float16*)(ws + OFF_H1);

  sniff_init<<<1, 256, 0, stream>>>((const unsigned*)x, mf, flags);
  cvt_bias<<<11, 256, 0, stream>>>(b0, b1, bd, biasf, mf);

  transpose_cast<<<dim3(K0P / 32, G4 / 32), dim3(32, 8), 0, stream>>>(W0, W0T, 900, 1024, 1024, K0P, mf);
  transpose_cast<<<dim3(UD / 32, G4 / 32), dim3(32, 8), 0, stream>>>(U0, U0T, 256, 1024, 1024, UD, mf);
  transpose_cast<<<dim3(UD / 32, G4 / 32), dim3(32, 8), 0, stream>>>(W1, W1T, 256, 1024, 1024, UD, mf);
  transpose_cast<<<dim3(UD / 32, G4 / 32), dim3(32, 8), 0, stream>>>(U1, U1T, 256, 1024, 1024, UD, mf);
  transpose_cast<<<dim3(UD / 32, NOUTP / 32), dim3(32, 8), 0, stream>>>(Wd, WdT, 256, 600, NOUTP, UD, mf);

  transpose_x<<<dim3(5, B_SZ), 256, 0, stream>>>(x, xt, mf);

  gemm_f16<0><<<dim3(G4 / 128, M_ROWS / 128), 256, 0, stream>>>(xt, W0T, biasf, zx0, G4, K0P, G4, mf);
  lstm_rec<<<32, 512, 0, stream>>>(zx0, U0T, h0, pay, flags);
  gemm_f16<0><<<dim3(G4 / 128, M_ROWS / 128), 256, 0, stream>>>(h0, W1T, biasf + 1024, zx1, G4, UD, G4, mf);
  lstm_rec<<<32, 512, 0, stream>>>(zx1, U1T, h1, pay, flags + 32);
  gemm_f16<1><<<dim3(NOUTP / 128, M_ROWS / 128), 256, 0, stream>>>(h1, WdT, biasf + 2048, d_out, NOUTP, UD, NOUT, mf);
}

// Round 4
// 747.522 us; speedup vs baseline: 2.2570x; 1.0017x over previous
//
#include <hip/hip_runtime.h>
#include <hip/hip_bf16.h>
#include <hip/hip_fp16.h>

// ---------------------------------------------------------------------------
// FCLSTM: x(256,300,64,3) -> transpose -> LSTM(900->256,relu) -> LSTM(256->256)
//         -> Dense(256->600) -> out (256,300,64,2)
// Phases:
//   P0 sniff dtype (f32 vs bf16 buffers)
//   P1 prep: bias cvt, weight transpose/cast to f16 "K-major" (N x K)
//   P2 transpose x -> xt (16384 x 928 f16, zero-padded K)
//   P3 GEMM zx0 = xt @ W0 + b0            (16384x1024, K=928)
//   P4 LSTM0 recurrence (paired-block, U in VGPRs, flag-free sentinel exchange)
//   P5 GEMM zx1 = h0 @ W1 + b1            (16384x1024, K=256, reuses zx0 buf)
//   P6 LSTM1 recurrence -> h1 seq
//   P7 GEMM out = h1 @ Wd + bd, scatter to (B,N,T,F) layout, f32 or bf16
// ---------------------------------------------------------------------------

typedef _Float16 half8 __attribute__((ext_vector_type(8)));
typedef float floatx4 __attribute__((ext_vector_type(4)));

#define B_SZ   256
#define T_STEPS 64
#define N_SEQ  300
#define M_ROWS 16384   // B*T
#define K0P    928     // padded 300*3=900
#define G4     1024    // 4*256 gate width
#define UD     256
#define NOUT   600
#define NOUTP  640

// f16 NaN x4 — h (= sigmoid * relu) can never be NaN, so this is unreachable
// as payload data. Aligned 8B stores are single-copy atomic through the fabric.
#define HSENT  0x7E007E007E007E00ULL

// ---- workspace layout (bytes) ----
#define OFF_MODE   ((size_t)0)
#define OFF_FLAGS  ((size_t)256)                   // 128 u32 (legacy, zeroed)
#define OFF_BIAS   ((size_t)768)                   // 2648 f32 (ends 11360 < 16384)
#define OFF_XT     ((size_t)16384)
#define SZ_XT      ((size_t)M_ROWS * K0P * 2)      // 30,408,704
#define OFF_W0T    (OFF_XT + SZ_XT)
#define SZ_W0T     ((size_t)G4 * K0P * 2)          // 1,900,544
#define OFF_U0T    (OFF_W0T + SZ_W0T)
#define SZ_UT      ((size_t)G4 * UD * 2)           // 524,288
#define OFF_W1T    (OFF_U0T + SZ_UT)
#define OFF_U1T    (OFF_W1T + SZ_UT)
#define OFF_WDT    (OFF_U1T + SZ_UT)
#define SZ_WDT     ((size_t)NOUTP * UD * 2)        // 327,680
#define OFF_HBUF   (OFF_WDT + SZ_WDT)
#define SZ_HBUF    ((size_t)16 * 2 * 64 * 512 * 8) // 8,388,608: [g][c][step][512 u64]
#define OFF_ZX0    (OFF_HBUF + SZ_HBUF)
#define SZ_ZX      ((size_t)M_ROWS * G4 * 2)       // 33,554,432 (shared by zx1)
#define OFF_H0     (OFF_ZX0 + SZ_ZX)
#define SZ_H       ((size_t)M_ROWS * UD * 2)       // 8,388,608
#define OFF_H1     (OFF_H0 + SZ_H)
#define WS_NEEDED  (OFF_H1 + SZ_H)

__device__ __forceinline__ float load_in(const void* p, size_t idx, int mode) {
  if (mode) {
    unsigned v = ((const unsigned short*)p)[idx];
    return __uint_as_float(v << 16);
  }
  return ((const float*)p)[idx];
}

// ---- P0: dtype sniff + flag zeroing --------------------------------------
__global__ void sniff_init(const unsigned* __restrict__ x, int* __restrict__ modeflag,
                           unsigned* __restrict__ flags) {
  __shared__ int cnt;
  if (threadIdx.x == 0) cnt = 0;
  __syncthreads();
  unsigned w = x[threadIdx.x];          // 256 words of x
  unsigned e = (w >> 8) & 0x7fu;        // bits 8..14: bf16 sign-dropped exp[7:1] if bf16
  if (e >= 0x3au && e <= 0x42u) atomicAdd(&cnt, 1);
  __syncthreads();
  if (threadIdx.x == 0) *modeflag = (cnt >= 128) ? 1 : 0;   // 1 = bf16 buffers
  if (threadIdx.x < 128) flags[threadIdx.x] = 0u;
}

// ---- sentinel pre-fill for the h-exchange payload (8MB) -------------------
__global__ void fill_sentinel(unsigned long long* __restrict__ p) {
  size_t i = (size_t)blockIdx.x * 256 + threadIdx.x;
  p[i] = HSENT;
}

// ---- P1a: bias convert ----------------------------------------------------
__global__ void cvt_bias(const void* __restrict__ b0, const void* __restrict__ b1,
                         const void* __restrict__ bd, float* __restrict__ outb,
                         const int* __restrict__ modeflag) {
  int mode = *modeflag;
  int i = blockIdx.x * 256 + threadIdx.x;
  if (i < 1024)       outb[i] = load_in(b0, i, mode);
  else if (i < 2048)  outb[i] = load_in(b1, i - 1024, mode);
  else if (i < 2648)  outb[i] = load_in(bd, i - 2048, mode);
}

// ---- P1b: generic transpose+cast: out[n*Kout+k] = in[k*Cin+n] (0 padded) --
__global__ void transpose_cast(const void* __restrict__ in, _Float16* __restrict__ out,
                               int Rin, int Cin, int Nout, int Kout,
                               const int* __restrict__ modeflag) {
  int mode = *modeflag;
  __shared__ float tile[32][33];
  int k0 = blockIdx.x * 32, n0 = blockIdx.y * 32;
  int tx = threadIdx.x, ty = threadIdx.y;
  #pragma unroll
  for (int i = 0; i < 32; i += 8) {
    int k = k0 + ty + i, n = n0 + tx;
    tile[ty + i][tx] = (k < Rin && n < Cin) ? load_in(in, (size_t)k * Cin + n, mode) : 0.f;
  }
  __syncthreads();
  #pragma unroll
  for (int i = 0; i < 32; i += 8) {
    int n = n0 + ty + i, k = k0 + tx;
    if (n < Nout && k < Kout)
      out[(size_t)n * Kout + k] = (_Float16)tile[tx][ty + i];
  }
}

// ---- P2: x (B,N,T,F) f32/bf16 -> xt (B*T, 928) f16 ------------------------
__global__ void transpose_x(const void* __restrict__ x, _Float16* __restrict__ xt,
                            const int* __restrict__ modeflag) {
  int mode = *modeflag;
  int b = blockIdx.y, ch = blockIdx.x;    // 5 chunks of 60 n each
  __shared__ _Float16 tile[60 * 192];     // [nn][t][f]
  int n0 = ch * 60;
  size_t basein = ((size_t)b * N_SEQ + n0) * 192;
  for (int i = threadIdx.x; i < 60 * 192; i += 256)
    tile[i] = (_Float16)load_in(x, basein + i, mode);
  __syncthreads();
  for (int i = threadIdx.x; i < 64 * 180; i += 256) {
    int t = i / 180, cz = i % 180;        // cz = nn*3+f
    int nn = cz / 3, f = cz % 3;
    xt[((size_t)b * 64 + t) * K0P + n0 * 3 + cz] = tile[nn * 192 + t * 3 + f];
  }
  if (ch == 4) {  // zero pad cols 900..927
    for (int i = threadIdx.x; i < 64 * 28; i += 256) {
      int t = i / 28, z = i % 28;
      xt[((size_t)b * 64 + t) * K0P + 900 + z] = (_Float16)0.f;
    }
  }
}

// ---- P3/P5/P7: f16 MFMA GEMM, 128x128 tile, 4 waves, BK=32 ----------------
// A: MxK f16 row-major. BT: NxK f16 row-major (i.e. B transposed, K-major).
// OUT_MODE 0: store f16 C[row*N+col] (+bias).  OUT_MODE 1: scatter to d_out.
template <int OUT_MODE>
__global__ __launch_bounds__(256)
void gemm_f16(const _Float16* __restrict__ A, const _Float16* __restrict__ BT,
              const float* __restrict__ bias, void* __restrict__ Cout,
              int N, int K, int Nreal, const int* __restrict__ modeflag) {
  __shared__ _Float16 As[128 * 40];
  __shared__ _Float16 Bs[128 * 40];
  int tid = threadIdx.x;
  int wv = tid >> 6, lane = tid & 63;
  int q = lane >> 4, l15 = lane & 15;
  int wm = wv >> 1, wn = wv & 1;
  int row0 = blockIdx.y * 128, col0 = blockIdx.x * 128;
  floatx4 acc[4][4] = {};
  int r_st = tid >> 1;            // staged row/col 0..127
  int c_st = (tid & 1) * 2;       // 16B chunk 0 or 2
  const _Float16* Arow = A + (size_t)(row0 + r_st) * K + c_st * 8;
  const _Float16* Brow = BT + (size_t)(col0 + r_st) * K + c_st * 8;
  _Float16* AsW = As + r_st * 40 + c_st * 8;
  _Float16* BsW = Bs + r_st * 40 + c_st * 8;

  for (int k0 = 0; k0 < K; k0 += 32) {
    __syncthreads();
    half8 a0 = *(const half8*)(Arow + k0);
    half8 a1 = *(const half8*)(Arow + k0 + 8);
    half8 b0v = *(const half8*)(Brow + k0);
    half8 b1v = *(const half8*)(Brow + k0 + 8);
    *(half8*)(AsW) = a0;  *(half8*)(AsW + 8) = a1;
    *(half8*)(BsW) = b0v; *(half8*)(BsW + 8) = b1v;
    __syncthreads();
    half8 af[4], bf[4];
    #pragma unroll
    for (int i = 0; i < 4; ++i)
      af[i] = *(const half8*)(As + (wm * 64 + i * 16 + l15) * 40 + q * 8);
    #pragma unroll
    for (int j = 0; j < 4; ++j)
      bf[j] = *(const half8*)(Bs + (wn * 64 + j * 16 + l15) * 40 + q * 8);
    #pragma unroll
    for (int i = 0; i < 4; ++i)
      #pragma unroll
      for (int j = 0; j < 4; ++j)
        acc[i][j] = __builtin_amdgcn_mfma_f32_16x16x32_f16(af[i], bf[j], acc[i][j], 0, 0, 0);
  }

  int mode = 0;
  if (OUT_MODE == 1) mode = *modeflag;
  #pragma unroll
  for (int j = 0; j < 4; ++j) {
    int col = col0 + wn * 64 + j * 16 + l15;
    float bv = (col < Nreal) ? bias[col] : 0.f;
    #pragma unroll
    for (int i = 0; i < 4; ++i) {
      int rowb = row0 + wm * 64 + i * 16 + q * 4;
      #pragma unroll
      for (int r = 0; r < 4; ++r) {
        float v = acc[i][j][r] + bv;
        int row = rowb + r;
        if (OUT_MODE == 0) {
          ((_Float16*)Cout)[(size_t)row * N + col] = (_Float16)v;
        } else {
          if (col < Nreal) {
            // row = b*64+t ; col = n*2+f ; out[((b*300+n)*64+t)*2+f]
            size_t idx = (size_t)(row >> 6) * 38400 + (size_t)(col >> 1) * 128
                       + (size_t)(row & 63) * 2 + (col & 1);
            if (mode) ((__hip_bfloat16*)Cout)[idx] = __float2bfloat16(v);
            else      ((float*)Cout)[idx] = v;
          }
        }
      }
    }
  }
}

// ---- P4/P6: LSTM recurrence (flag-free sentinel handshake) ----------------
// 16 groups (16 batch rows each) x 2 blocks (128 units each). 512 thr = 8 waves.
// Wave w holds U columns for its 16 units x 4 gates as MFMA B-frags in VGPRs.
// Cross-block h exchange: each step writes a FRESH 4KB slot (64 slots, no
// reuse) of relaxed agent-scope u64 stores; readiness is carried by the data
// itself — slots are pre-filled with an f16-NaN sentinel the payload can never
// equal, and the consumer polls exactly the 8 u64s it needs (batched loads).
// No flags, no fences, no barriers on the cross-block path.
// Own-half h exchange: XOR-swizzled LDS, double-buffered, one barrier/step.
__global__ __launch_bounds__(512, 2)
void lstm_rec(const _Float16* __restrict__ zx, const _Float16* __restrict__ UT,
              _Float16* __restrict__ hseq, unsigned long long* __restrict__ pay) {
  int tid = threadIdx.x;
  int wv = tid >> 6, lane = tid & 63;
  int q = lane >> 4, l15 = lane & 15;
  int c = blockIdx.x >> 4;       // pair half 0/1
  int g = blockIdx.x & 15;       // batch group
  int ubase = c * 128 + wv * 16; // wave's unit base within 256
  int ucol = ubase + l15;

  __shared__ _Float16 hlds[2][16 * 128];   // own-half h, XOR-swizzled, 2 x 4KB

  half8 uf[4][8];
  #pragma unroll
  for (int G = 0; G < 4; ++G) {
    const _Float16* Urow = UT + (size_t)(G * 256 + ucol) * UD;
    #pragma unroll
    for (int s = 0; s < 8; ++s)
      uf[G][s] = *(const half8*)(Urow + s * 32 + q * 8);
  }
  half8 hf[8];
  #pragma unroll
  for (int s = 0; s < 8; ++s) hf[s] = (half8)(_Float16)0.f;
  floatx4 cst = {0.f, 0.f, 0.f, 0.f};

  unsigned long long* mypay = pay + (size_t)(g * 2 + c) * 64 * 512;
  const unsigned long long* ppay = pay + (size_t)(g * 2 + (1 - c)) * 64 * 512;

  // transpose-target coords: this lane will own (row, colquad) after the
  // in-quad 4x4 f16 transpose. row = batch row 0..15, colquad = 4 cols.
  int row = q * 4 + (lane & 3);
  int cq  = l15 & 12;
  int payi  = row * 32 + ((wv * 16 + cq) >> 2);                        // u64 idx
  int ldswb = (row * 256 + (wv * 16 + cq) * 2) ^ ((row & 7) << 4);     // swz byte
  unsigned long long* hsp =
      (unsigned long long*)(hseq + ((size_t)(g * 16 + row) * 64) * UD + ubase + cq);
  const _Float16* zb = zx + (size_t)(g * 16 + q * 4) * 64 * G4 + ucol;

  // zx prefetch registers (one timestep ahead)
  unsigned short zpre[16];
  #pragma unroll
  for (int G = 0; G < 4; ++G)
    #pragma unroll
    for (int r = 0; r < 4; ++r)
      zpre[G * 4 + r] = *(const unsigned short*)(zb + r * (64 * G4) + G * 256);

  for (int t = 0; t < 64; ++t) {
    floatx4 accv[4] = {};
    // own-half slices first so LDS-sourced MFMAs lead
    if (c == 0) {
      #pragma unroll
      for (int s = 0; s < 8; ++s) {
        accv[0] = __builtin_amdgcn_mfma_f32_16x16x32_f16(hf[s], uf[0][s], accv[0], 0, 0, 0);
        accv[1] = __builtin_amdgcn_mfma_f32_16x16x32_f16(hf[s], uf[1][s], accv[1], 0, 0, 0);
        accv[2] = __builtin_amdgcn_mfma_f32_16x16x32_f16(hf[s], uf[2][s], accv[2], 0, 0, 0);
        accv[3] = __builtin_amdgcn_mfma_f32_16x16x32_f16(hf[s], uf[3][s], accv[3], 0, 0, 0);
      }
    } else {
      #pragma unroll
      for (int ss = 0; ss < 8; ++ss) {
        int s = (ss + 4) & 7;   // 4,5,6,7,0,1,2,3 — constant after unroll
        accv[0] = __builtin_amdgcn_mfma_f32_16x16x32_f16(hf[s], uf[0][s], accv[0], 0, 0, 0);
        accv[1] = __builtin_amdgcn_mfma_f32_16x16x32_f16(hf[s], uf[1][s], accv[1], 0, 0, 0);
        accv[2] = __builtin_amdgcn_mfma_f32_16x16x32_f16(hf[s], uf[2][s], accv[2], 0, 0, 0);
        accv[3] = __builtin_amdgcn_mfma_f32_16x16x32_f16(hf[s], uf[3][s], accv[3], 0, 0, 0);
      }
    }

    _Float16 hh[4];
    #pragma unroll
    for (int r = 0; r < 4; ++r) {
      float zi = accv[0][r] + (float)__builtin_bit_cast(_Float16, zpre[0 + r]);
      float zf = accv[1][r] + (float)__builtin_bit_cast(_Float16, zpre[4 + r]);
      float zg = accv[2][r] + (float)__builtin_bit_cast(_Float16, zpre[8 + r]);
      float zo = accv[3][r] + (float)__builtin_bit_cast(_Float16, zpre[12 + r]);
      float ig = 1.f / (1.f + __expf(-zi));
      float fg = 1.f / (1.f + __expf(-zf));
      float gg = zg > 0.f ? zg : 0.f;
      float og = 1.f / (1.f + __expf(-zo));
      float cn = fg * cst[r] + ig * gg;
      cst[r] = cn;
      hh[r] = (_Float16)(og * (cn > 0.f ? cn : 0.f));
    }

    // 4x4 in-quad f16 transpose: lane(q,l15) holds col ucol rows q*4..+3;
    // after 2 shfl_xor each lane holds row q*4+(lane&3), cols ubase+cq..+3 (u64)
    unsigned A  = ((unsigned)__builtin_bit_cast(unsigned short, hh[1]) << 16)
                |  (unsigned)__builtin_bit_cast(unsigned short, hh[0]);
    unsigned Bq = ((unsigned)__builtin_bit_cast(unsigned short, hh[3]) << 16)
                |  (unsigned)__builtin_bit_cast(unsigned short, hh[2]);
    unsigned T  = __shfl_xor((lane & 2) ? A : Bq, 2, 64);
    unsigned X0 = (lane & 2) ? T : A;    // left col pair (rows r,r+1)
    unsigned X1 = (lane & 2) ? Bq : T;   // right col pair
    unsigned W  = (X0 & 0xffffu) | (X1 << 16);          // even row of pair
    unsigned X  = (X0 >> 16) | (X1 & 0xffff0000u);      // odd  row of pair
    unsigned R  = __shfl_xor((lane & 1) ? W : X, 1, 64);
    unsigned lo, hi;
    if (lane & 1) { lo = (R & 0xffffu) | (X << 16); hi = (R >> 16) | (X & 0xffff0000u); }
    else          { lo = (W & 0xffffu) | (R << 16); hi = (W >> 16) | (R & 0xffff0000u); }
    unsigned long long hp = ((unsigned long long)hi << 32) | lo;

    hsp[(size_t)t * 64] = hp;                    // hseq: fire-and-forget

    if (t < 63) {
      int par = t & 1;
      // payload -> fresh per-step slot (relaxed agent store, fire-and-forget;
      // the data itself is the ready signal: it can never equal HSENT)
      __hip_atomic_store(mypay + (size_t)t * 512 + payi, hp, __ATOMIC_RELAXED,
                         __HIP_MEMORY_SCOPE_AGENT);
      // own half into swizzled LDS
      *(unsigned long long*)((char*)hlds + par * 4096 + ldswb) = hp;
      // prefetch zx for t+1 (drained together with stores by the barrier)
      #pragma unroll
      for (int G = 0; G < 4; ++G)
        #pragma unroll
        for (int r = 0; r < 4; ++r)
          zpre[G * 4 + r] =
              *(const unsigned short*)(zb + r * (64 * G4) + (t + 1) * G4 + G * 256);
      __syncthreads();   // LDS visibility for own-half exchange

      // partner payload: batched 8-load poll until all non-sentinel
      const unsigned long long* pp = ppay + (size_t)t * 512 + (l15 * 32 + q * 2);
      unsigned long long v0, v1, v2, v3, v4, v5, v6, v7;
      for (;;) {
        v0 = __hip_atomic_load(pp + 0,  __ATOMIC_RELAXED, __HIP_MEMORY_SCOPE_AGENT);
        v1 = __hip_atomic_load(pp + 1,  __ATOMIC_RELAXED, __HIP_MEMORY_SCOPE_AGENT);
        v2 = __hip_atomic_load(pp + 8,  __ATOMIC_RELAXED, __HIP_MEMORY_SCOPE_AGENT);
        v3 = __hip_atomic_load(pp + 9,  __ATOMIC_RELAXED, __HIP_MEMORY_SCOPE_AGENT);
        v4 = __hip_atomic_load(pp + 16, __ATOMIC_RELAXED, __HIP_MEMORY_SCOPE_AGENT);
        v5 = __hip_atomic_load(pp + 17, __ATOMIC_RELAXED, __HIP_MEMORY_SCOPE_AGENT);
        v6 = __hip_atomic_load(pp + 24, __ATOMIC_RELAXED, __HIP_MEMORY_SCOPE_AGENT);
        v7 = __hip_atomic_load(pp + 25, __ATOMIC_RELAXED, __HIP_MEMORY_SCOPE_AGENT);
        if (v0 != HSENT && v1 != HSENT && v2 != HSENT && v3 != HSENT &&
            v4 != HSENT && v5 != HSENT && v6 != HSENT && v7 != HSENT) break;
        __builtin_amdgcn_s_sleep(1);
      }
      union { unsigned long long u[2]; half8 v; } cv0, cv1, cv2, cv3;
      cv0.u[0] = v0; cv0.u[1] = v1;
      cv1.u[0] = v2; cv1.u[1] = v3;
      cv2.u[0] = v4; cv2.u[1] = v5;
      cv3.u[0] = v6; cv3.u[1] = v7;
      if (c == 0) {
        hf[4] = cv0.v; hf[5] = cv1.v; hf[6] = cv2.v; hf[7] = cv3.v;
        #pragma unroll
        for (int sl = 0; sl < 4; ++sl) {     // own half (LDS) -> slices 0..3
          int rb = (l15 * 256 + sl * 64 + q * 16) ^ ((l15 & 7) << 4);
          hf[sl] = *(const half8*)((const char*)hlds + par * 4096 + rb);
        }
      } else {
        hf[0] = cv0.v; hf[1] = cv1.v; hf[2] = cv2.v; hf[3] = cv3.v;
        #pragma unroll
        for (int sl = 0; sl < 4; ++sl) {     // own half (LDS) -> slices 4..7
          int rb = (l15 * 256 + sl * 64 + q * 16) ^ ((l15 & 7) << 4);
          hf[4 + sl] = *(const half8*)((const char*)hlds + par * 4096 + rb);
        }
      }
    }
  }
}

// ---------------------------------------------------------------------------
extern "C" void kernel_launch(void* const* d_in, const int* in_sizes, int n_in,
                              void* d_out, int out_size, void* d_ws, size_t ws_size,
                              hipStream_t stream) {
  if (ws_size < WS_NEEDED) return;  // fail loudly via wrong output rather than OOB

  const void* x  = d_in[0];
  const void* W0 = d_in[1];
  const void* U0 = d_in[2];
  const void* b0 = d_in[3];
  const void* W1 = d_in[4];
  const void* U1 = d_in[5];
  const void* b1 = d_in[6];
  const void* Wd = d_in[7];
  const void* bd = d_in[8];

  char* ws = (char*)d_ws;
  int*       mf    = (int*)(ws + OFF_MODE);
  unsigned*  flags = (unsigned*)(ws + OFF_FLAGS);
  float*     biasf = (float*)(ws + OFF_BIAS);
  _Float16*  xt    = (_Float16*)(ws + OFF_XT);
  _Float16*  W0T   = (_Float16*)(ws + OFF_W0T);
  _Float16*  U0T   = (_Float16*)(ws + OFF_U0T);
  _Float16*  W1T   = (_Float16*)(ws + OFF_W1T);
  _Float16*  U1T   = (_Float16*)(ws + OFF_U1T);
  _Float16*  WdT   = (_Float16*)(ws + OFF_WDT);
  unsigned long long* pay = (unsigned long long*)(ws + OFF_HBUF);
  _Float16*  zx0   = (_Float16*)(ws + OFF_ZX0);
  _Float16*  h0    = (_Float16*)(ws + OFF_H0);
  _Float16*  zx1   = (_Float16*)(ws + OFF_ZX0);   // reuses zx0 (dead after LSTM0)
  _Float16*  h1    = (_Float16*)(ws + OFF_H1);

  sniff_init<<<1, 256, 0, stream>>>((const unsigned*)x, mf, flags);
  cvt_bias<<<11, 256, 0, stream>>>(b0, b1, bd, biasf, mf);

  transpose_cast<<<dim3(K0P / 32, G4 / 32), dim3(32, 8), 0, stream>>>(W0, W0T, 900, 1024, 1024, K0P, mf);
  transpose_cast<<<dim3(UD / 32, G4 / 32), dim3(32, 8), 0, stream>>>(U0, U0T, 256, 1024, 1024, UD, mf);
  transpose_cast<<<dim3(UD / 32, G4 / 32), dim3(32, 8), 0, stream>>>(W1, W1T, 256, 1024, 1024, UD, mf);
  transpose_cast<<<dim3(UD / 32, G4 / 32), dim3(32, 8), 0, stream>>>(U1, U1T, 256, 1024, 1024, UD, mf);
  transpose_cast<<<dim3(UD / 32, NOUTP / 32), dim3(32, 8), 0, stream>>>(Wd, WdT, 256, 600, NOUTP, UD, mf);

  transpose_x<<<dim3(5, B_SZ), 256, 0, stream>>>(x, xt, mf);
  fill_sentinel<<<4096, 256, 0, stream>>>(pay);   // before LSTM0

  gemm_f16<0><<<dim3(G4 / 128, M_ROWS / 128), 256, 0, stream>>>(xt, W0T, biasf, zx0, G4, K0P, G4, mf);
  lstm_rec<<<32, 512, 0, stream>>>(zx0, U0T, h0, pay);
  fill_sentinel<<<4096, 256, 0, stream>>>(pay);   // re-arm for LSTM1
  gemm_f16<0><<<dim3(G4 / 128, M_ROWS / 128), 256, 0, stream>>>(h0, W1T, biasf + 1024, zx1, G4, UD, G4, mf);
  lstm_rec<<<32, 512, 0, stream>>>(zx1, U1T, h1, pay);
  gemm_f16<1><<<dim3(NOUTP / 128, M_ROWS / 128), 256, 0, stream>>>(h1, WdT, biasf + 2048, d_out, NOUTP, UD, NOUT, mf);
}